// Round 1
// baseline (91.912 us; speedup 1.0000x reference)
//
#include <hip/hip_runtime.h>
#include <hip/hip_bf16.h>
#include <cstdint>
#include <cstddef>

#define N_NODES 8192
#define IN_DIM  128
#define OUT_DIM 64
#define LRELU_ALPHA 0.2f
#define S_SLICES 4

using f32x16 = __attribute__((ext_vector_type(16))) float;
using bf16x8 = __attribute__((ext_vector_type(8))) short;

static __device__ __forceinline__ unsigned short f2bf(float x) {
    union { float f; unsigned u; } v; v.f = x;
    unsigned r = v.u + 0x7FFFu + ((v.u >> 16) & 1u);  // RNE
    return (unsigned short)(r >> 16);
}

// ---------------------------------------------------------------------------
// K1: h = x@W ; s = h@a_src ; d = h@a_dst ; Hpack = bf16(h) in MFMA-B layout.
// Block = 256 thr = 4 waves; wave w handles 8 rows, lane = feature f (0..63).
// Hpack layout: [jb][fb][lane][e] 16B units, jb = j>>4, fb = f>>5,
// lane = (f&31) + 32*((j>>3)&1), e = j&7  -> B-frag load is hp[(jb*2+fb)*64+l].
// ---------------------------------------------------------------------------
__global__ __launch_bounds__(256) void gat_prep(
    const float* __restrict__ x, const float* __restrict__ W,
    const float* __restrict__ a,
    float* __restrict__ svec, float* __restrict__ dvec,
    unsigned short* __restrict__ hpack)
{
    const int tid = threadIdx.x;
    const int w   = tid >> 6;
    const int f   = tid & 63;
    const int i0  = blockIdx.x * 32 + w * 8;   // 8 consecutive rows, 8-aligned

    float acc[8];
#pragma unroll
    for (int r = 0; r < 8; ++r) acc[r] = 0.f;

    for (int k = 0; k < IN_DIM; k += 4) {
        const float w0 = W[(k + 0) * OUT_DIM + f];
        const float w1 = W[(k + 1) * OUT_DIM + f];
        const float w2 = W[(k + 2) * OUT_DIM + f];
        const float w3 = W[(k + 3) * OUT_DIM + f];
#pragma unroll
        for (int r = 0; r < 8; ++r) {
            const float4 xv = *reinterpret_cast<const float4*>(
                x + (size_t)(i0 + r) * IN_DIM + k);
            acc[r] = fmaf(xv.x, w0, acc[r]);
            acc[r] = fmaf(xv.y, w1, acc[r]);
            acc[r] = fmaf(xv.z, w2, acc[r]);
            acc[r] = fmaf(xv.w, w3, acc[r]);
        }
    }

    // s_i, d_i via full-wave (64-lane) shuffle reduction over features
    const float asrc = a[f];
    const float adst = a[OUT_DIM + f];
#pragma unroll
    for (int r = 0; r < 8; ++r) {
        float sv = acc[r] * asrc;
        float dv = acc[r] * adst;
#pragma unroll
        for (int off = 32; off >= 1; off >>= 1) {
            sv += __shfl_xor(sv, off);
            dv += __shfl_xor(dv, off);
        }
        if (f == 0) { svec[i0 + r] = sv; dvec[i0 + r] = dv; }
    }

    // pack h -> bf16 B-fragment-native layout (one 16B store per thread)
    const int jb    = i0 >> 4;
    const int jhalf = (i0 >> 3) & 1;
    const int fb    = f >> 5;
    const int lidx  = (f & 31) + 32 * jhalf;
    union { unsigned short us[8]; int4 v; } pk;
#pragma unroll
    for (int r = 0; r < 8; ++r) pk.us[r] = f2bf(acc[r]);
    *reinterpret_cast<int4*>(hpack + ((size_t)(jb * 2 + fb) * 64 + lidx) * 8) = pk.v;
}

// ---------------------------------------------------------------------------
// K2: one pass over adj. Grid (256 row-blocks, 4 j-slices) x 256 thr (4 waves).
// Wave = 32 rows x 512 j's. Per 16-j step: build P A-fragment elementwise
// (p = adj ? exp(lrelu(s_i + d_j)) : 0), 2x mfma_32x32x16_bf16 (f-blocks),
// fp32 denominator per lane. LDS-reduce 4 waves -> slice partial to ws.
// ---------------------------------------------------------------------------
__global__ __launch_bounds__(256, 4) void gat_main(
    const int* __restrict__ adj,
    const float* __restrict__ svec, const float* __restrict__ dvec,
    const unsigned short* __restrict__ hpack,
    float* __restrict__ pO, float* __restrict__ pDen)
{
    __shared__ float red[4][32][64];
    __shared__ float redden[4][32];

    const int tid = threadIdx.x;
    const int w   = tid >> 6;
    const int l   = tid & 63;
    const int rb  = blockIdx.x;
    const int sl  = blockIdx.y;
    const int row = l & 31;      // A-fragment row (query i within block)
    const int kh  = l >> 5;      // k-half
    const int i0  = rb * 32;
    const int jbase = sl * 2048 + w * 512;

    const float s_i = svec[i0 + row];
    const int* adjrow = adj + (size_t)(i0 + row) * N_NODES;
    const bf16x8* hp = reinterpret_cast<const bf16x8*>(hpack);

    f32x16 acc0, acc1;
#pragma unroll
    for (int r = 0; r < 16; ++r) { acc0[r] = 0.f; acc1[r] = 0.f; }
    float den = 0.f;

    for (int jt = 0; jt < 512; jt += 16) {
        const int jcol = jbase + jt;
        const int j0   = jcol + kh * 8;          // this lane's 8 j's
        const int4  a0 = *reinterpret_cast<const int4*>(adjrow + j0);
        const int4  a1 = *reinterpret_cast<const int4*>(adjrow + j0 + 4);
        const float4 d0 = *reinterpret_cast<const float4*>(dvec + j0);
        const float4 d1 = *reinterpret_cast<const float4*>(dvec + j0 + 4);
        const int jb = jcol >> 4;
        const bf16x8 b0 = hp[(jb * 2 + 0) * 64 + l];
        const bf16x8 b1 = hp[(jb * 2 + 1) * 64 + l];

        const float dd[8] = {d0.x, d0.y, d0.z, d0.w, d1.x, d1.y, d1.z, d1.w};
        const int   ia[8] = {a0.x, a0.y, a0.z, a0.w, a1.x, a1.y, a1.z, a1.w};

        bf16x8 af;
#pragma unroll
        for (int e = 0; e < 8; ++e) {
            float ev = s_i + dd[e];
            ev = fmaxf(ev, LRELU_ALPHA * ev);    // leaky-relu: max(x, 0.2x)
            float pv = __expf(ev);               // no max-subtraction needed (|e|<~8)
            pv = (ia[e] > 0) ? pv : 0.f;
            den += pv;
            af[e] = (short)f2bf(pv);
        }
        acc0 = __builtin_amdgcn_mfma_f32_32x32x16_bf16(af, b0, acc0, 0, 0, 0);
        acc1 = __builtin_amdgcn_mfma_f32_32x32x16_bf16(af, b1, acc1, 0, 0, 0);
    }

    // scatter acc to LDS using verified C/D layout: col=l&31, row=(r&3)+8*(r>>2)+4*kh
#pragma unroll
    for (int r = 0; r < 16; ++r) {
        const int orow = (r & 3) + 8 * (r >> 2) + 4 * kh;
        red[w][orow][row]      = acc0[r];
        red[w][orow][32 + row] = acc1[r];
    }
    const float dtot = den + __shfl_xor(den, 32);   // combine the two k-halves
    if (l < 32) redden[w][l] = dtot;
    __syncthreads();

    // reduce the 4 waves, write slice partial
    float* po = pO + ((size_t)rb * S_SLICES + sl) * 2048;
    const float* rf = &red[0][0][0];
    for (int e = tid; e < 2048; e += 256)
        po[e] = rf[e] + rf[2048 + e] + rf[4096 + e] + rf[6144 + e];
    if (tid < 32) {
        pDen[((size_t)rb * S_SLICES + sl) * 32 + tid] =
            redden[0][tid] + redden[1][tid] + redden[2][tid] + redden[3][tid];
    }
}

// ---------------------------------------------------------------------------
// K3: sum 4 slice partials, normalize, ELU, write fp32 output.
// ---------------------------------------------------------------------------
__global__ __launch_bounds__(256) void gat_final(
    const float* __restrict__ pO, const float* __restrict__ pDen,
    float* __restrict__ out)
{
    const int idx = blockIdx.x * 256 + threadIdx.x;
    const int i = idx >> 6;
    const int f = idx & 63;
    const int rb = i >> 5;
    const int r  = i & 31;
    const float* po = pO + (size_t)rb * S_SLICES * 2048 + r * 64 + f;
    const float v = po[0] + po[2048] + po[4096] + po[6144];
    const float* pd = pDen + (size_t)rb * S_SLICES * 32 + r;
    const float dsum = pd[0] + pd[32] + pd[64] + pd[96];
    const float o = v / dsum;
    out[idx] = (o > 0.f) ? o : expm1f(o);   // jax.nn.elu, alpha=1
}

extern "C" void kernel_launch(void* const* d_in, const int* in_sizes, int n_in,
                              void* d_out, int out_size, void* d_ws, size_t ws_size,
                              hipStream_t stream)
{
    const float* x   = (const float*)d_in[0];
    const int*   adj = (const int*)d_in[1];
    const float* W   = (const float*)d_in[2];
    const float* a   = (const float*)d_in[3];
    float* out = (float*)d_out;

    // workspace carve-up (~9.3 MB total)
    float* svec = (float*)d_ws;                                  // 8192 f32
    float* dvec = svec + N_NODES;                                // 8192 f32
    unsigned short* hpack = (unsigned short*)(dvec + N_NODES);   // 1 MB bf16
    float* pO = (float*)(hpack + (size_t)N_NODES * OUT_DIM);     // 256*4*2048 f32 = 8 MB
    float* pDen = pO + (size_t)256 * S_SLICES * 2048;            // 32768 f32

    gat_prep<<<256, 256, 0, stream>>>(x, W, a, svec, dvec, hpack);
    gat_main<<<dim3(256, S_SLICES), 256, 0, stream>>>(adj, svec, dvec, hpack, pO, pDen);
    gat_final<<<(N_NODES * OUT_DIM) / 256, 256, 0, stream>>>(pO, pDen, out);
}

// Round 2
// 72.129 us; speedup vs baseline: 1.2743x; 1.2743x over previous
//
#include <hip/hip_runtime.h>
#include <hip/hip_bf16.h>
#include <cstdint>
#include <cstddef>

#define N_NODES 8192
#define IN_DIM  128
#define OUT_DIM 64
#define LRELU_ALPHA 0.2f
#define S_SLICES 4
#define LOG2E 1.44269504f

using f32x16 = __attribute__((ext_vector_type(16))) float;
using bf16x8 = __attribute__((ext_vector_type(8))) short;

typedef const __attribute__((address_space(1))) int* gas_ptr;
typedef __attribute__((address_space(3))) int* las_ptr;

static __device__ __forceinline__ unsigned short f2bf(float x) {
    union { float f; unsigned u; } v; v.f = x;
    unsigned r = v.u + 0x7FFFu + ((v.u >> 16) & 1u);  // RNE (used in prep only)
    return (unsigned short)(r >> 16);
}

// ---------------------------------------------------------------------------
// K1: h = x@W ; svec = (h@a_src)*log2e ; dvec = (h@a_dst)*log2e ;
// hpack = bf16(h) in MFMA-B layout. Grid 1024 x 256thr: block = 8 rows,
// k-split across the 4 waves (wave w does k in [32w,32w+32)), LDS reduce.
// ---------------------------------------------------------------------------
__global__ __launch_bounds__(256) void gat_prep(
    const float* __restrict__ x, const float* __restrict__ W,
    const float* __restrict__ a,
    float* __restrict__ svec, float* __restrict__ dvec,
    unsigned short* __restrict__ hpack)
{
    __shared__ float shA[4][8][64];
    const int tid = threadIdx.x;
    const int w   = tid >> 6;
    const int f   = tid & 63;
    const int i0  = blockIdx.x * 8;

    float acc[8];
#pragma unroll
    for (int r = 0; r < 8; ++r) acc[r] = 0.f;

    const int k0 = w * 32;
#pragma unroll 2
    for (int k = k0; k < k0 + 32; k += 4) {
        const float w0 = W[(k + 0) * OUT_DIM + f];
        const float w1 = W[(k + 1) * OUT_DIM + f];
        const float w2 = W[(k + 2) * OUT_DIM + f];
        const float w3 = W[(k + 3) * OUT_DIM + f];
#pragma unroll
        for (int r = 0; r < 8; ++r) {
            const float4 xv = *reinterpret_cast<const float4*>(
                x + (size_t)(i0 + r) * IN_DIM + k);
            acc[r] = fmaf(xv.x, w0, acc[r]);
            acc[r] = fmaf(xv.y, w1, acc[r]);
            acc[r] = fmaf(xv.z, w2, acc[r]);
            acc[r] = fmaf(xv.w, w3, acc[r]);
        }
    }
#pragma unroll
    for (int r = 0; r < 8; ++r) shA[w][r][f] = acc[r];
    __syncthreads();

    if (w == 0) {
        // pack h -> bf16 B-fragment-native layout (one 16B store per lane)
        union { unsigned short us[8]; int4 v; } pk;
#pragma unroll
        for (int r = 0; r < 8; ++r) {
            const float hv = shA[0][r][f] + shA[1][r][f] + shA[2][r][f] + shA[3][r][f];
            pk.us[r] = f2bf(hv);
        }
        const int jb    = i0 >> 4;
        const int jhalf = (i0 >> 3) & 1;
        const int fb    = f >> 5;
        const int lidx  = (f & 31) + 32 * jhalf;
        *reinterpret_cast<int4*>(hpack + ((size_t)(jb * 2 + fb) * 64 + lidx) * 8) = pk.v;
    } else if (w == 1) {
        const float asrc = a[f];
#pragma unroll
        for (int r = 0; r < 8; ++r) {
            const float hv = shA[0][r][f] + shA[1][r][f] + shA[2][r][f] + shA[3][r][f];
            float sv = hv * asrc;
#pragma unroll
            for (int off = 32; off >= 1; off >>= 1) sv += __shfl_xor(sv, off);
            if (f == 0) svec[i0 + r] = sv * LOG2E;
        }
    } else if (w == 2) {
        const float adst = a[OUT_DIM + f];
#pragma unroll
        for (int r = 0; r < 8; ++r) {
            const float hv = shA[0][r][f] + shA[1][r][f] + shA[2][r][f] + shA[3][r][f];
            float dv = hv * adst;
#pragma unroll
            for (int off = 32; off >= 1; off >>= 1) dv += __shfl_xor(dv, off);
            if (f == 0) dvec[i0 + r] = dv * LOG2E;
        }
    }
}

// ---------------------------------------------------------------------------
// K2: one pass over adj, LDS-staged. Grid (256 rb, 4 sl) x 256thr (4 waves).
// Block = 32 rows x 2048 j. Super-step = 128 j: stage 32x128 ints (16KB) via
// global_load_lds width-16 (2 contiguous rows per inst, XOR-swizzled source),
// double-buffered; each wave computes its 32-j subrange (2 MFMA-steps).
// p = exp2(lrelu(s'_i + d'_j)) masked by adj; truncated to bf16; den uses the
// SAME truncated p so softmax rounding bias cancels.
// ---------------------------------------------------------------------------
__global__ __launch_bounds__(256, 4) void gat_main(
    const int* __restrict__ adj,
    const float* __restrict__ svec, const float* __restrict__ dvec,
    const unsigned short* __restrict__ hpack,
    float* __restrict__ pO, float* __restrict__ pDen)
{
    union SH {
        int tiles[2][32 * 128];                                  // 2 x 16KB
        struct { float red[4][32][64]; float redden[4][32]; } r; // 32.5KB
    };
    __shared__ SH sh;

    const int tid = threadIdx.x;
    const int w   = tid >> 6;
    const int l   = tid & 63;
    const int rb  = blockIdx.x;
    const int sl  = blockIdx.y;
    const int row = l & 31;      // A-fragment row (query i within block)
    const int kh  = l >> 5;      // k-half
    const int i0  = rb * 32;
    const int jwin = sl * 2048;

    const float s_i = svec[i0 + row];   // already * log2e
    const bf16x8* hp = reinterpret_cast<const bf16x8*>(hpack);

    // staging: wave w issues 4 insts, each = 2 rows x 512B contiguous.
    // LDS is linear [row][128 ints]; the 16B-unit column is XOR-swizzled on
    // the GLOBAL source (c_g = c_p ^ (row&7)) and un-swizzled on the ds_read.
    auto stage = [&](int buf, int ss) {
        const int jt0 = jwin + ss * 128;
#pragma unroll
        for (int q = 0; q < 4; ++q) {
            const int r0   = (w * 4 + q) * 2;
            const int lrow = r0 + (l >> 5);
            const int cp   = l & 31;
            const int cg   = cp ^ (lrow & 7);
            const int* gsrc = adj + (size_t)(i0 + lrow) * N_NODES + jt0 + cg * 4;
            int* ldst = &sh.tiles[buf][r0 * 128];  // wave-uniform base
            __builtin_amdgcn_global_load_lds((gas_ptr)gsrc, (las_ptr)ldst, 16, 0, 0);
        }
    };

    f32x16 acc0, acc1;
#pragma unroll
    for (int r = 0; r < 16; ++r) { acc0[r] = 0.f; acc1[r] = 0.f; }
    float den = 0.f;

    stage(0, 0);
    __syncthreads();

    for (int ss = 0; ss < 16; ++ss) {
        const int buf = ss & 1;
        if (ss + 1 < 16) stage(buf ^ 1, ss + 1);

        const int jt0 = jwin + ss * 128;
#pragma unroll
        for (int st = 0; st < 2; ++st) {
            const int jo = w * 32 + st * 16;   // tile-local j offset
            const int jg = jt0 + jo;           // global j
            const int c0 = (jo >> 2) + kh * 2; // logical 16B unit
            const int4 A0 = *reinterpret_cast<const int4*>(
                &sh.tiles[buf][row * 128 + ((c0    ) ^ (row & 7)) * 4]);
            const int4 A1 = *reinterpret_cast<const int4*>(
                &sh.tiles[buf][row * 128 + ((c0 + 1) ^ (row & 7)) * 4]);
            const int j0 = jg + kh * 8;
            const float4 d0 = *reinterpret_cast<const float4*>(dvec + j0);
            const float4 d1 = *reinterpret_cast<const float4*>(dvec + j0 + 4);
            const int jb = jg >> 4;
            const bf16x8 b0 = hp[(jb * 2 + 0) * 64 + l];
            const bf16x8 b1 = hp[(jb * 2 + 1) * 64 + l];

            const float dd[8] = {d0.x, d0.y, d0.z, d0.w, d1.x, d1.y, d1.z, d1.w};
            const int   ia[8] = {A0.x, A0.y, A0.z, A0.w, A1.x, A1.y, A1.z, A1.w};

            bf16x8 af;
#pragma unroll
            for (int e = 0; e < 8; ++e) {
                float ev = s_i + dd[e];                     // log2-domain logit
                ev = fmaxf(ev, LRELU_ALPHA * ev);           // lrelu (scale>0 commutes)
                float pv = __builtin_amdgcn_exp2f(ev);
                pv = (ia[e] > 0) ? pv : 0.f;
                union { float f; unsigned u; } pu; pu.f = pv;
                pu.u &= 0xFFFF0000u;                        // truncate to bf16
                den += pu.f;                                // denominator CONSISTENT with numerator
                af[e] = (short)(pu.u >> 16);
            }
            acc0 = __builtin_amdgcn_mfma_f32_32x32x16_bf16(af, b0, acc0, 0, 0, 0);
            acc1 = __builtin_amdgcn_mfma_f32_32x32x16_bf16(af, b1, acc1, 0, 0, 0);
        }
        __syncthreads();  // drains vmcnt -> next buffer staged; reads of buf done
    }

    // scatter acc via verified C/D layout: col=l&31, row=(r&3)+8*(r>>2)+4*kh
#pragma unroll
    for (int r = 0; r < 16; ++r) {
        const int orow = (r & 3) + 8 * (r >> 2) + 4 * kh;
        sh.r.red[w][orow][row]      = acc0[r];
        sh.r.red[w][orow][32 + row] = acc1[r];
    }
    const float dtot = den + __shfl_xor(den, 32);
    if (l < 32) sh.r.redden[w][l] = dtot;
    __syncthreads();

    float* po = pO + ((size_t)rb * S_SLICES + sl) * 2048;
    const float* rf = &sh.r.red[0][0][0];
    for (int e = tid; e < 2048; e += 256)
        po[e] = rf[e] + rf[2048 + e] + rf[4096 + e] + rf[6144 + e];
    if (tid < 32) {
        pDen[((size_t)rb * S_SLICES + sl) * 32 + tid] =
            sh.r.redden[0][tid] + sh.r.redden[1][tid] +
            sh.r.redden[2][tid] + sh.r.redden[3][tid];
    }
}

// ---------------------------------------------------------------------------
// K3: sum 4 slice partials, normalize, ELU, write fp32 output.
// ---------------------------------------------------------------------------
__global__ __launch_bounds__(256) void gat_final(
    const float* __restrict__ pO, const float* __restrict__ pDen,
    float* __restrict__ out)
{
    const int idx = blockIdx.x * 256 + threadIdx.x;
    const int i = idx >> 6;
    const int f = idx & 63;
    const int rb = i >> 5;
    const int r  = i & 31;
    const float* po = pO + (size_t)rb * S_SLICES * 2048 + r * 64 + f;
    const float v = po[0] + po[2048] + po[4096] + po[6144];
    const float* pd = pDen + (size_t)rb * S_SLICES * 32 + r;
    const float dsum = pd[0] + pd[32] + pd[64] + pd[96];
    const float o = v / dsum;
    out[idx] = (o > 0.f) ? o : expm1f(o);   // jax.nn.elu, alpha=1
}

extern "C" void kernel_launch(void* const* d_in, const int* in_sizes, int n_in,
                              void* d_out, int out_size, void* d_ws, size_t ws_size,
                              hipStream_t stream)
{
    const float* x   = (const float*)d_in[0];
    const int*   adj = (const int*)d_in[1];
    const float* W   = (const float*)d_in[2];
    const float* a   = (const float*)d_in[3];
    float* out = (float*)d_out;

    float* svec = (float*)d_ws;                                  // 8192 f32
    float* dvec = svec + N_NODES;                                // 8192 f32
    unsigned short* hpack = (unsigned short*)(dvec + N_NODES);   // 1 MB bf16
    float* pO = (float*)(hpack + (size_t)N_NODES * OUT_DIM);     // 8 MB
    float* pDen = pO + (size_t)256 * S_SLICES * 2048;            // 128 KB

    gat_prep<<<N_NODES / 8, 256, 0, stream>>>(x, W, a, svec, dvec, hpack);
    gat_main<<<dim3(256, S_SLICES), 256, 0, stream>>>(adj, svec, dvec, hpack, pO, pDen);
    gat_final<<<(N_NODES * OUT_DIM) / 256, 256, 0, stream>>>(pO, pDen, out);
}